// Round 9
// baseline (105.549 us; speedup 1.0000x reference)
//
#include <hip/hip_runtime.h>

#define N_ATOMS 262144
#define NGRAPH  2048
#define INV_SCALE 0.17677669529663687f  // 1/sqrt(32)

typedef float f32x2 __attribute__((ext_vector_type(2)));
typedef float f32x4 __attribute__((ext_vector_type(4)));

// CDNA packed fp32 (VOP3P), R5-verified.
__device__ __forceinline__ f32x2 pk_mul(f32x2 a, f32x2 b) {
  f32x2 d; asm("v_pk_mul_f32 %0, %1, %2" : "=v"(d) : "v"(a), "v"(b)); return d;
}
__device__ __forceinline__ f32x2 pk_fma(f32x2 a, f32x2 b, f32x2 c) {
  f32x2 d; asm("v_pk_fma_f32 %0, %1, %2, %3" : "=v"(d) : "v"(a), "v"(b), "v"(c)); return d;
}
__device__ __forceinline__ f32x2 pk_fma_blo(f32x2 a, f32x2 b, f32x2 c) {
  f32x2 d; asm("v_pk_fma_f32 %0, %1, %2, %3 op_sel_hi:[0,1,1]"
               : "=v"(d) : "v"(a), "v"(b), "v"(c)); return d;
}
__device__ __forceinline__ f32x2 pk_fma_bhi(f32x2 a, f32x2 b, f32x2 c) {
  f32x2 d; asm("v_pk_fma_f32 %0, %1, %2, %3 op_sel:[1,0,0]"
               : "=v"(d) : "v"(a), "v"(b), "v"(c)); return d;
}
__device__ __forceinline__ f32x4 ldnt4(const float* p) {
  return __builtin_nontemporal_load(reinterpret_cast<const f32x4*>(p));
}

// gfx950 cross-lane swaps (VALU, ~5cy — not DS). Semantics (LLVM):
// pl32: vdst[32..63] <-> vsrc[0..31];  pl16: vdst rows 1,3 <-> vsrc rows 0,2.
__device__ __forceinline__ void pl32_swap(float& a, float& b) {
  asm("v_permlane32_swap_b32 %0, %1" : "+v"(a), "+v"(b));
}
__device__ __forceinline__ void pl16_swap(float& a, float& b) {
  asm("v_permlane16_swap_b32 %0, %1" : "+v"(a), "+v"(b));
}
template <int CTRL>
__device__ __forceinline__ float dpp_f(float x) {
  return __int_as_float(__builtin_amdgcn_mov_dpp(__float_as_int(x), CTRL, 0xf, 0xf, true));
}
#define DPP_XOR1 0xB1   // quad_perm [1,0,3,2]
#define DPP_XOR2 0x4E   // quad_perm [2,3,0,1]
#define DPP_ROR8 0x128  // row_ror:8 == xor 8 within 16-lane row

// fold: 8 head-partials/lane -> full dot of head h at every lane,
// h = bit5 + 2*bit4 + 4*bit3 of lane. 1 DS op total (xor4), rest VALU.
__device__ __forceinline__ float fold8_dpp(float v[8], int lane) {
  float w0, w1, w2, w3;
  { float a = v[0], b = v[1]; pl32_swap(a, b); w0 = a + b; }  // head 0|1 by bit5
  { float a = v[2], b = v[3]; pl32_swap(a, b); w1 = a + b; }
  { float a = v[4], b = v[5]; pl32_swap(a, b); w2 = a + b; }
  { float a = v[6], b = v[7]; pl32_swap(a, b); w3 = a + b; }
  float u0, u1;
  { float a = w0, b = w1; pl16_swap(a, b); u0 = a + b; }      // + 2*bit4
  { float a = w2, b = w3; pl16_swap(a, b); u1 = a + b; }
  bool m3 = (lane & 8) != 0;
  float snd = m3 ? u0 : u1;
  float keep = m3 ? u1 : u0;
  float r = keep + dpp_f<DPP_ROR8>(snd);                      // + 4*bit3
  r += dpp_f<DPP_XOR1>(r);
  r += dpp_f<DPP_XOR2>(r);
  r += __int_as_float(__builtin_amdgcn_ds_swizzle(__float_as_int(r), 0x101F));  // xor4
  return r;
}

// broadcast: lane's own-head e -> e8[k] = e of head k, all lanes. Zero DS.
__device__ __forceinline__ void bcast8_dpp(float ev, int lane, float e8[8]) {
  bool m3 = (lane & 8) != 0;
  float o = dpp_f<DPP_ROR8>(ev);   // e of head h^4
  float E0 = m3 ? o : ev;          // head bit5+2*bit4
  float E1 = m3 ? ev : o;          // head bit5+2*bit4+4
  float Fa = E0, Fb = E0; pl16_swap(Fa, Fb);  // Fa: head bit5,   Fb: head bit5+2
  float Fc = E1, Fd = E1; pl16_swap(Fc, Fd);  // Fc: head bit5+4, Fd: head bit5+6
  float g0 = Fa, g1 = Fa; pl32_swap(g0, g1);  // heads 0,1
  float g2 = Fb, g3 = Fb; pl32_swap(g2, g3);  // heads 2,3
  float g4 = Fc, g5 = Fc; pl32_swap(g4, g5);  // heads 4,5
  float g6 = Fd, g7 = Fd; pl32_swap(g6, g7);  // heads 6,7
  e8[0] = g0; e8[1] = g1; e8[2] = g2; e8[3] = g3;
  e8[4] = g4; e8[5] = g5; e8[6] = g6; e8[7] = g7;
}

// ---------------- K1: fused prep (blocks 0-7) + bounds (blocks 8-15).
__global__ void k_pre(const float* __restrict__ Wk, const float* __restrict__ bk,
                      const float* __restrict__ q, const int* __restrict__ batch,
                      float* __restrict__ P, float* __restrict__ c,
                      int* __restrict__ bounds) {
  if (blockIdx.x < 8) {
    int h = blockIdx.x, i = threadIdx.x;
    float s = 0.f;
    #pragma unroll
    for (int d = 0; d < 32; ++d)
      s = fmaf(Wk[i * 256 + h * 32 + d], q[h * 32 + d], s);
    P[h * 256 + i] = s;
    if (i == 0) {
      float cc = 0.f;
      #pragma unroll
      for (int d = 0; d < 32; ++d) cc = fmaf(bk[h * 32 + d], q[h * 32 + d], cc);
      c[h] = cc;
    }
  } else {
    int g = (blockIdx.x - 8) * 256 + threadIdx.x;
    if (g >= NGRAPH) return;
    int lo = 0, hi = N_ATOMS;
    while (lo < hi) {
      int mid = (lo + hi) >> 1;
      if (batch[mid] < g) lo = mid + 1; else hi = mid;
    }
    bounds[2 * g] = lo;
    if (g > 0) bounds[2 * g - 1] = lo;
    if (g == NGRAPH - 1) bounds[2 * g + 1] = N_ATOMS;
  }
}

// ---------------- K2: fused single-pass scores + exp + weighted accumulate.
// R5/R8-verified math; cross-lane reduce+broadcast moved from DS-pipe shuffles
// to VALU DPP/permlane-swap (1 ds_swizzle per atom remains). Head ownership
// h = bit5 + 2*bit4 + 4*bit3 of lane.
__global__ __launch_bounds__(256) void k_fused(const float* __restrict__ x,
                                               const float* __restrict__ P,
                                               const float* __restrict__ c,
                                               const int* __restrict__ bounds,
                                               float* __restrict__ Ag) {
  int b = blockIdx.x;
  int s = bounds[2 * b], e = bounds[2 * b + 1];
  int t = threadIdx.x, lane = t & 63, wv = t >> 6;
  int h = ((lane >> 5) & 1) | ((lane >> 3) & 2) | ((lane >> 1) & 4);

  f32x2 Pl2[8][2];
  #pragma unroll
  for (int k = 0; k < 8; ++k) {
    f32x4 pv = *reinterpret_cast<const f32x4*>(P + k * 256 + 4 * lane);
    Pl2[k][0] = __builtin_shufflevector(pv, pv, 0, 1);
    Pl2[k][1] = __builtin_shufflevector(pv, pv, 2, 3);
  }
  float cl = c[h];

  f32x2 A2[8][2];
  #pragma unroll
  for (int k = 0; k < 8; ++k) { A2[k][0] = (f32x2)0.f; A2[k][1] = (f32x2)0.f; }
  float dacc = 0.f;

  __shared__ float Asc[4][2][256];  // 8 KB chunked epilogue buffer
  __shared__ float dws[4][8];
  __shared__ float dinvs[8];

  for (int n0 = s + 2 * wv; n0 < e; n0 += 8) {
    bool has2 = (n0 + 1) < e;
    int n1 = has2 ? n0 + 1 : n0;
    f32x4 xq0 = ldnt4(x + (size_t)n0 * 256 + 4 * lane);
    f32x4 xq1 = ldnt4(x + (size_t)n1 * 256 + 4 * lane);
    f32x2 x0lo = __builtin_shufflevector(xq0, xq0, 0, 1);
    f32x2 x0hi = __builtin_shufflevector(xq0, xq0, 2, 3);
    f32x2 x1lo = __builtin_shufflevector(xq1, xq1, 0, 1);
    f32x2 x1hi = __builtin_shufflevector(xq1, xq1, 2, 3);

    float acc0[8], acc1[8];
    #pragma unroll
    for (int k = 0; k < 8; ++k) {
      f32x2 p0 = pk_fma(x0hi, Pl2[k][1], pk_mul(x0lo, Pl2[k][0]));
      f32x2 p1 = pk_fma(x1hi, Pl2[k][1], pk_mul(x1lo, Pl2[k][0]));
      acc0[k] = p0[0] + p0[1];
      acc1[k] = p1[0] + p1[1];
    }
    float r0 = fold8_dpp(acc0, lane);
    float r1 = fold8_dpp(acc1, lane);
    float ev0 = __expf((r0 + cl) * INV_SCALE);
    float ev1 = __expf((r1 + cl) * INV_SCALE);
    ev1 = has2 ? ev1 : 0.f;
    dacc += ev0 + ev1;

    float e80[8], e81[8];
    bcast8_dpp(ev0, lane, e80);
    bcast8_dpp(ev1, lane, e81);
    f32x2 ea[4], eb[4];
    #pragma unroll
    for (int j = 0; j < 4; ++j) {
      ea[j][0] = e80[2 * j]; ea[j][1] = e80[2 * j + 1];
      eb[j][0] = e81[2 * j]; eb[j][1] = e81[2 * j + 1];
    }
    #pragma unroll
    for (int j = 0; j < 4; ++j) {
      A2[2*j][0]   = pk_fma_blo(ea[j], x0lo, A2[2*j][0]);
      A2[2*j][1]   = pk_fma_blo(ea[j], x0hi, A2[2*j][1]);
      A2[2*j+1][0] = pk_fma_bhi(ea[j], x0lo, A2[2*j+1][0]);
      A2[2*j+1][1] = pk_fma_bhi(ea[j], x0hi, A2[2*j+1][1]);
      A2[2*j][0]   = pk_fma_blo(eb[j], x1lo, A2[2*j][0]);
      A2[2*j][1]   = pk_fma_blo(eb[j], x1hi, A2[2*j][1]);
      A2[2*j+1][0] = pk_fma_bhi(eb[j], x1lo, A2[2*j+1][0]);
      A2[2*j+1][1] = pk_fma_bhi(eb[j], x1hi, A2[2*j+1][1]);
    }
  }

  // ---- epilogue: denom, then 4 head-pair passes of cross-wave reduce.
  if ((lane & 7) == 0) dws[wv][h] = dacc;
  __syncthreads();
  if (t < 8) {
    float ds = dws[0][t] + dws[1][t] + dws[2][t] + dws[3][t];
    dinvs[t] = ds > 0.f ? 1.0f / ds : 0.f;
  }
  #pragma unroll
  for (int p = 0; p < 4; ++p) {
    float4 a0, a1;
    a0.x = A2[2*p][0][0];   a0.y = A2[2*p][0][1];
    a0.z = A2[2*p][1][0];   a0.w = A2[2*p][1][1];
    a1.x = A2[2*p+1][0][0]; a1.y = A2[2*p+1][0][1];
    a1.z = A2[2*p+1][1][0]; a1.w = A2[2*p+1][1][1];
    *reinterpret_cast<float4*>(&Asc[wv][0][4 * lane]) = a0;
    *reinterpret_cast<float4*>(&Asc[wv][1][4 * lane]) = a1;
    __syncthreads();
    float v0 = Asc[0][0][t] + Asc[1][0][t] + Asc[2][0][t] + Asc[3][0][t];
    float v1 = Asc[0][1][t] + Asc[1][1][t] + Asc[2][1][t] + Asc[3][1][t];
    Ag[(size_t)b * 2048 + (2*p) * 256 + t]   = v0 * dinvs[2*p];
    Ag[(size_t)b * 2048 + (2*p+1) * 256 + t] = v1 * dinvs[2*p+1];
    __syncthreads();
  }
}

// ---------------- K5: att = A . Wv + bv (nonempty), out = att . Wo + bo
__global__ __launch_bounds__(256) void k_out(const float* __restrict__ Ag,
                                             const int* __restrict__ bounds,
                                             const float* __restrict__ Wv,
                                             const float* __restrict__ bv,
                                             const float* __restrict__ Wo,
                                             const float* __restrict__ bo,
                                             float* __restrict__ out) {
  __shared__ float Alds[4 * 2048];   // 32 KB
  __shared__ float attlds[4 * 256];  // 4 KB
  __shared__ float eflag[4];
  int b0 = blockIdx.x * 4;
  int t = threadIdx.x;
  #pragma unroll
  for (int r = 0; r < 32; ++r) {
    int idx = r * 256 + t;
    Alds[idx] = Ag[(size_t)b0 * 2048 + idx];
  }
  if (t < 4) {
    int s = bounds[2 * (b0 + t)], e = bounds[2 * (b0 + t) + 1];
    eflag[t] = (e > s) ? 1.0f : 0.0f;
  }
  __syncthreads();
  int h = t >> 5;
  float bvk = bv[t];
  float acc[4];
  #pragma unroll
  for (int g = 0; g < 4; ++g) acc[g] = 0.f;
  for (int i4 = 0; i4 < 64; ++i4) {
    float aa[4][4];
    #pragma unroll
    for (int g = 0; g < 4; ++g) {
      float4 v = *reinterpret_cast<const float4*>(&Alds[g * 2048 + h * 256 + i4 * 4]);
      aa[g][0] = v.x; aa[g][1] = v.y; aa[g][2] = v.z; aa[g][3] = v.w;
    }
    #pragma unroll
    for (int j = 0; j < 4; ++j) {
      float wvv = Wv[(size_t)(i4 * 4 + j) * 256 + t];
      #pragma unroll
      for (int g = 0; g < 4; ++g) acc[g] = fmaf(aa[g][j], wvv, acc[g]);
    }
  }
  #pragma unroll
  for (int g = 0; g < 4; ++g) attlds[g * 256 + t] = acc[g] + bvk * eflag[g];
  __syncthreads();
  float boj = bo[t];
  float o[4];
  #pragma unroll
  for (int g = 0; g < 4; ++g) o[g] = boj;
  for (int k4 = 0; k4 < 64; ++k4) {
    float aa[4][4];
    #pragma unroll
    for (int g = 0; g < 4; ++g) {
      float4 v = *reinterpret_cast<const float4*>(&attlds[g * 256 + k4 * 4]);
      aa[g][0] = v.x; aa[g][1] = v.y; aa[g][2] = v.z; aa[g][3] = v.w;
    }
    #pragma unroll
    for (int j = 0; j < 4; ++j) {
      float wo = Wo[(size_t)(k4 * 4 + j) * 256 + t];
      #pragma unroll
      for (int g = 0; g < 4; ++g) o[g] = fmaf(aa[g][j], wo, o[g]);
    }
  }
  #pragma unroll
  for (int g = 0; g < 4; ++g) out[(size_t)(b0 + g) * 256 + t] = o[g];
}

extern "C" void kernel_launch(void* const* d_in, const int* in_sizes, int n_in,
                              void* d_out, int out_size, void* d_ws, size_t ws_size,
                              hipStream_t stream) {
  const float* x   = (const float*)d_in[0];
  const int*   bat = (const int*)d_in[1];
  const float* q   = (const float*)d_in[2];
  const float* Wk  = (const float*)d_in[3];
  const float* bk  = (const float*)d_in[4];
  const float* Wv  = (const float*)d_in[5];
  const float* bv  = (const float*)d_in[6];
  const float* Wo  = (const float*)d_in[7];
  const float* bo  = (const float*)d_in[8];
  float* out = (float*)d_out;

  float* ws = (float*)d_ws;
  float* P      = ws;                 // 2048 floats
  float* c      = ws + 2048;          // 8 floats
  int*   bounds = (int*)(ws + 4096);  // 4096 ints
  float* Ag     = ws + 8192;          // 2048*2048 floats

  k_pre<<<16, 256, 0, stream>>>(Wk, bk, q, bat, P, c, bounds);
  k_fused<<<NGRAPH, 256, 0, stream>>>(x, P, c, bounds, Ag);
  k_out<<<NGRAPH / 4, 256, 0, stream>>>(Ag, bounds, Wv, bv, Wo, bo, out);
}

// Round 10
// 101.359 us; speedup vs baseline: 1.0413x; 1.0413x over previous
//
#include <hip/hip_runtime.h>

#define N_ATOMS 262144
#define NGRAPH  2048
#define INV_SCALE 0.17677669529663687f  // 1/sqrt(32)

typedef float f32x2 __attribute__((ext_vector_type(2)));
typedef float f32x4 __attribute__((ext_vector_type(4)));

// CDNA packed fp32 (VOP3P), R5-verified.
__device__ __forceinline__ f32x2 pk_mul(f32x2 a, f32x2 b) {
  f32x2 d; asm("v_pk_mul_f32 %0, %1, %2" : "=v"(d) : "v"(a), "v"(b)); return d;
}
__device__ __forceinline__ f32x2 pk_fma(f32x2 a, f32x2 b, f32x2 c) {
  f32x2 d; asm("v_pk_fma_f32 %0, %1, %2, %3" : "=v"(d) : "v"(a), "v"(b), "v"(c)); return d;
}
__device__ __forceinline__ f32x2 pk_fma_blo(f32x2 a, f32x2 b, f32x2 c) {
  f32x2 d; asm("v_pk_fma_f32 %0, %1, %2, %3 op_sel_hi:[0,1,1]"
               : "=v"(d) : "v"(a), "v"(b), "v"(c)); return d;
}
__device__ __forceinline__ f32x2 pk_fma_bhi(f32x2 a, f32x2 b, f32x2 c) {
  f32x2 d; asm("v_pk_fma_f32 %0, %1, %2, %3 op_sel:[1,0,0]"
               : "=v"(d) : "v"(a), "v"(b), "v"(c)); return d;
}
__device__ __forceinline__ f32x4 ldnt4(const float* p) {
  return __builtin_nontemporal_load(reinterpret_cast<const f32x4*>(p));
}

// ---------------- K1: fused prep (blocks 0-7) + bounds (blocks 8-15).
__global__ void k_pre(const float* __restrict__ Wk, const float* __restrict__ bk,
                      const float* __restrict__ q, const int* __restrict__ batch,
                      float* __restrict__ P, float* __restrict__ c,
                      int* __restrict__ bounds) {
  if (blockIdx.x < 8) {
    int h = blockIdx.x, i = threadIdx.x;
    float s = 0.f;
    #pragma unroll
    for (int d = 0; d < 32; ++d)
      s = fmaf(Wk[i * 256 + h * 32 + d], q[h * 32 + d], s);
    P[h * 256 + i] = s;
    if (i == 0) {
      float cc = 0.f;
      #pragma unroll
      for (int d = 0; d < 32; ++d) cc = fmaf(bk[h * 32 + d], q[h * 32 + d], cc);
      c[h] = cc;
    }
  } else {
    int g = (blockIdx.x - 8) * 256 + threadIdx.x;
    if (g >= NGRAPH) return;
    int lo = 0, hi = N_ATOMS;
    while (lo < hi) {
      int mid = (lo + hi) >> 1;
      if (batch[mid] < g) lo = mid + 1; else hi = mid;
    }
    bounds[2 * g] = lo;
    if (g > 0) bounds[2 * g - 1] = lo;
    if (g == NGRAPH - 1) bounds[2 * g + 1] = N_ATOMS;
  }
}

// transpose-reduce: 8 head-partials/lane over 64 lanes -> full dot of head h at
// every lane (head ownership h(lane) = bit-mix of lane bits 3,4,5). R2-verified.
__device__ __forceinline__ float fold8(float acc[8], int lane) {
  {
    int m = lane & 8;
    float nw[4];
    #pragma unroll
    for (int j = 0; j < 4; ++j) {
      float snd = m ? acc[j] : acc[j + 4];
      float rcv = __shfl_xor(snd, 8, 64);
      nw[j] = (m ? acc[j + 4] : acc[j]) + rcv;
    }
    #pragma unroll
    for (int j = 0; j < 4; ++j) acc[j] = nw[j];
  }
  {
    int m = lane & 16;
    float nw[2];
    #pragma unroll
    for (int j = 0; j < 2; ++j) {
      float snd = m ? acc[j] : acc[j + 2];
      float rcv = __shfl_xor(snd, 16, 64);
      nw[j] = (m ? acc[j + 2] : acc[j]) + rcv;
    }
    acc[0] = nw[0]; acc[1] = nw[1];
  }
  float r;
  {
    int m = lane & 32;
    float snd = m ? acc[0] : acc[1];
    float rcv = __shfl_xor(snd, 32, 64);
    r = (m ? acc[1] : acc[0]) + rcv;
  }
  r += __shfl_xor(r, 1, 64);
  r += __shfl_xor(r, 2, 64);
  r += __shfl_xor(r, 4, 64);
  return r;
}

// ---------------- K2: fused single-pass scores + exp + weighted accumulate.
// R8-verified structure (fold8 shfl + elds e-table + chunked epilogue + NT
// loads) with ONE change: depth-1 software pipeline — next iteration's x
// loads issue before this iteration's compute, removing HBM latency from the
// steady-state dependence chain (hipcc won't do this across iterations).
__global__ __launch_bounds__(256) void k_fused(const float* __restrict__ x,
                                               const float* __restrict__ P,
                                               const float* __restrict__ c,
                                               const int* __restrict__ bounds,
                                               float* __restrict__ Ag) {
  int b = blockIdx.x;
  int s = bounds[2 * b], e = bounds[2 * b + 1];
  int t = threadIdx.x, lane = t & 63, wv = t >> 6;
  int h = ((lane >> 1) & 4) | ((lane >> 3) & 2) | ((lane >> 5) & 1);

  f32x2 Pl2[8][2];
  #pragma unroll
  for (int k = 0; k < 8; ++k) {
    f32x4 pv = *reinterpret_cast<const f32x4*>(P + k * 256 + 4 * lane);
    Pl2[k][0] = __builtin_shufflevector(pv, pv, 0, 1);
    Pl2[k][1] = __builtin_shufflevector(pv, pv, 2, 3);
  }
  float cl = c[h];

  f32x2 A2[8][2];
  #pragma unroll
  for (int k = 0; k < 8; ++k) { A2[k][0] = (f32x2)0.f; A2[k][1] = (f32x2)0.f; }
  float dacc = 0.f;

  __shared__ float elds[4][2][8];   // wave-private e-table
  __shared__ float Asc[4][2][256];  // 8 KB chunked epilogue buffer
  __shared__ float dws[4][8];
  __shared__ float dinvs[8];

  const float* xl = x + 4 * lane;

  int n0 = s + 2 * wv;
  f32x4 xq0 = {0.f, 0.f, 0.f, 0.f}, xq1 = {0.f, 0.f, 0.f, 0.f};
  if (n0 < e) {
    int n1 = (n0 + 1) < e ? n0 + 1 : n0;
    xq0 = ldnt4(xl + (size_t)n0 * 256);
    xq1 = ldnt4(xl + (size_t)n1 * 256);
  }

  for (; n0 < e; n0 += 8) {
    // ---- prefetch next pair (wave-uniform guard)
    f32x4 nx0 = xq0, nx1 = xq1;
    int m0 = n0 + 8;
    if (m0 < e) {
      int m1 = (m0 + 1) < e ? m0 + 1 : m0;
      nx0 = ldnt4(xl + (size_t)m0 * 256);
      nx1 = ldnt4(xl + (size_t)m1 * 256);
    }
    bool has2 = (n0 + 1) < e;
    f32x2 x0lo = __builtin_shufflevector(xq0, xq0, 0, 1);
    f32x2 x0hi = __builtin_shufflevector(xq0, xq0, 2, 3);
    f32x2 x1lo = __builtin_shufflevector(xq1, xq1, 0, 1);
    f32x2 x1hi = __builtin_shufflevector(xq1, xq1, 2, 3);

    float acc0[8], acc1[8];
    #pragma unroll
    for (int k = 0; k < 8; ++k) {
      f32x2 p0 = pk_fma(x0hi, Pl2[k][1], pk_mul(x0lo, Pl2[k][0]));
      f32x2 p1 = pk_fma(x1hi, Pl2[k][1], pk_mul(x1lo, Pl2[k][0]));
      acc0[k] = p0[0] + p0[1];
      acc1[k] = p1[0] + p1[1];
    }
    float r0 = fold8(acc0, lane);
    float r1 = fold8(acc1, lane);
    float ev0 = __expf((r0 + cl) * INV_SCALE);
    float ev1 = __expf((r1 + cl) * INV_SCALE);
    ev1 = has2 ? ev1 : 0.f;
    dacc += ev0 + ev1;

    if ((lane & 7) == 0) {
      elds[wv][0][h] = ev0;
      elds[wv][1][h] = ev1;
    }
    f32x4 ea03 = *reinterpret_cast<const f32x4*>(&elds[wv][0][0]);
    f32x4 ea47 = *reinterpret_cast<const f32x4*>(&elds[wv][0][4]);
    f32x4 eb03 = *reinterpret_cast<const f32x4*>(&elds[wv][1][0]);
    f32x4 eb47 = *reinterpret_cast<const f32x4*>(&elds[wv][1][4]);
    f32x2 ea[4] = { __builtin_shufflevector(ea03, ea03, 0, 1),
                    __builtin_shufflevector(ea03, ea03, 2, 3),
                    __builtin_shufflevector(ea47, ea47, 0, 1),
                    __builtin_shufflevector(ea47, ea47, 2, 3) };
    f32x2 eb[4] = { __builtin_shufflevector(eb03, eb03, 0, 1),
                    __builtin_shufflevector(eb03, eb03, 2, 3),
                    __builtin_shufflevector(eb47, eb47, 0, 1),
                    __builtin_shufflevector(eb47, eb47, 2, 3) };
    #pragma unroll
    for (int j = 0; j < 4; ++j) {
      A2[2*j][0]   = pk_fma_blo(ea[j], x0lo, A2[2*j][0]);
      A2[2*j][1]   = pk_fma_blo(ea[j], x0hi, A2[2*j][1]);
      A2[2*j+1][0] = pk_fma_bhi(ea[j], x0lo, A2[2*j+1][0]);
      A2[2*j+1][1] = pk_fma_bhi(ea[j], x0hi, A2[2*j+1][1]);
      A2[2*j][0]   = pk_fma_blo(eb[j], x1lo, A2[2*j][0]);
      A2[2*j][1]   = pk_fma_blo(eb[j], x1hi, A2[2*j][1]);
      A2[2*j+1][0] = pk_fma_bhi(eb[j], x1lo, A2[2*j+1][0]);
      A2[2*j+1][1] = pk_fma_bhi(eb[j], x1hi, A2[2*j+1][1]);
    }
    xq0 = nx0; xq1 = nx1;
  }

  // ---- epilogue: denom, then 4 head-pair passes of cross-wave reduce.
  if ((lane & 7) == 0) dws[wv][h] = dacc;
  __syncthreads();
  if (t < 8) {
    float ds = dws[0][t] + dws[1][t] + dws[2][t] + dws[3][t];
    dinvs[t] = ds > 0.f ? 1.0f / ds : 0.f;
  }
  #pragma unroll
  for (int p = 0; p < 4; ++p) {
    float4 a0, a1;
    a0.x = A2[2*p][0][0];   a0.y = A2[2*p][0][1];
    a0.z = A2[2*p][1][0];   a0.w = A2[2*p][1][1];
    a1.x = A2[2*p+1][0][0]; a1.y = A2[2*p+1][0][1];
    a1.z = A2[2*p+1][1][0]; a1.w = A2[2*p+1][1][1];
    *reinterpret_cast<float4*>(&Asc[wv][0][4 * lane]) = a0;
    *reinterpret_cast<float4*>(&Asc[wv][1][4 * lane]) = a1;
    __syncthreads();
    float v0 = Asc[0][0][t] + Asc[1][0][t] + Asc[2][0][t] + Asc[3][0][t];
    float v1 = Asc[0][1][t] + Asc[1][1][t] + Asc[2][1][t] + Asc[3][1][t];
    Ag[(size_t)b * 2048 + (2*p) * 256 + t]   = v0 * dinvs[2*p];
    Ag[(size_t)b * 2048 + (2*p+1) * 256 + t] = v1 * dinvs[2*p+1];
    __syncthreads();
  }
}

// ---------------- K5: att = A . Wv + bv (nonempty), out = att . Wo + bo
__global__ __launch_bounds__(256) void k_out(const float* __restrict__ Ag,
                                             const int* __restrict__ bounds,
                                             const float* __restrict__ Wv,
                                             const float* __restrict__ bv,
                                             const float* __restrict__ Wo,
                                             const float* __restrict__ bo,
                                             float* __restrict__ out) {
  __shared__ float Alds[4 * 2048];   // 32 KB
  __shared__ float attlds[4 * 256];  // 4 KB
  __shared__ float eflag[4];
  int b0 = blockIdx.x * 4;
  int t = threadIdx.x;
  #pragma unroll
  for (int r = 0; r < 32; ++r) {
    int idx = r * 256 + t;
    Alds[idx] = Ag[(size_t)b0 * 2048 + idx];
  }
  if (t < 4) {
    int s = bounds[2 * (b0 + t)], e = bounds[2 * (b0 + t) + 1];
    eflag[t] = (e > s) ? 1.0f : 0.0f;
  }
  __syncthreads();
  int h = t >> 5;
  float bvk = bv[t];
  float acc[4];
  #pragma unroll
  for (int g = 0; g < 4; ++g) acc[g] = 0.f;
  for (int i4 = 0; i4 < 64; ++i4) {
    float aa[4][4];
    #pragma unroll
    for (int g = 0; g < 4; ++g) {
      float4 v = *reinterpret_cast<const float4*>(&Alds[g * 2048 + h * 256 + i4 * 4]);
      aa[g][0] = v.x; aa[g][1] = v.y; aa[g][2] = v.z; aa[g][3] = v.w;
    }
    #pragma unroll
    for (int j = 0; j < 4; ++j) {
      float wvv = Wv[(size_t)(i4 * 4 + j) * 256 + t];
      #pragma unroll
      for (int g = 0; g < 4; ++g) acc[g] = fmaf(aa[g][j], wvv, acc[g]);
    }
  }
  #pragma unroll
  for (int g = 0; g < 4; ++g) attlds[g * 256 + t] = acc[g] + bvk * eflag[g];
  __syncthreads();
  float boj = bo[t];
  float o[4];
  #pragma unroll
  for (int g = 0; g < 4; ++g) o[g] = boj;
  for (int k4 = 0; k4 < 64; ++k4) {
    float aa[4][4];
    #pragma unroll
    for (int g = 0; g < 4; ++g) {
      float4 v = *reinterpret_cast<const float4*>(&attlds[g * 256 + k4 * 4]);
      aa[g][0] = v.x; aa[g][1] = v.y; aa[g][2] = v.z; aa[g][3] = v.w;
    }
    #pragma unroll
    for (int j = 0; j < 4; ++j) {
      float wo = Wo[(size_t)(k4 * 4 + j) * 256 + t];
      #pragma unroll
      for (int g = 0; g < 4; ++g) o[g] = fmaf(aa[g][j], wo, o[g]);
    }
  }
  #pragma unroll
  for (int g = 0; g < 4; ++g) out[(size_t)(b0 + g) * 256 + t] = o[g];
}

extern "C" void kernel_launch(void* const* d_in, const int* in_sizes, int n_in,
                              void* d_out, int out_size, void* d_ws, size_t ws_size,
                              hipStream_t stream) {
  const float* x   = (const float*)d_in[0];
  const int*   bat = (const int*)d_in[1];
  const float* q   = (const float*)d_in[2];
  const float* Wk  = (const float*)d_in[3];
  const float* bk  = (const float*)d_in[4];
  const float* Wv  = (const float*)d_in[5];
  const float* bv  = (const float*)d_in[6];
  const float* Wo  = (const float*)d_in[7];
  const float* bo  = (const float*)d_in[8];
  float* out = (float*)d_out;

  float* ws = (float*)d_ws;
  float* P      = ws;                 // 2048 floats
  float* c      = ws + 2048;          // 8 floats
  int*   bounds = (int*)(ws + 4096);  // 4096 ints
  float* Ag     = ws + 8192;          // 2048*2048 floats

  k_pre<<<16, 256, 0, stream>>>(Wk, bk, q, bat, P, c, bounds);
  k_fused<<<NGRAPH, 256, 0, stream>>>(x, P, c, bounds, Ag);
  k_out<<<NGRAPH / 4, 256, 0, stream>>>(Ag, bounds, Wv, bv, Wo, bo, out);
}

// Round 11
// 97.467 us; speedup vs baseline: 1.0829x; 1.0399x over previous
//
#include <hip/hip_runtime.h>

#define N_ATOMS 262144
#define NGRAPH  2048
#define INV_SCALE 0.17677669529663687f  // 1/sqrt(32)

typedef float f32x2 __attribute__((ext_vector_type(2)));
typedef float f32x4 __attribute__((ext_vector_type(4)));

// CDNA packed fp32 (VOP3P), R5-verified.
__device__ __forceinline__ f32x2 pk_mul(f32x2 a, f32x2 b) {
  f32x2 d; asm("v_pk_mul_f32 %0, %1, %2" : "=v"(d) : "v"(a), "v"(b)); return d;
}
__device__ __forceinline__ f32x2 pk_fma(f32x2 a, f32x2 b, f32x2 c) {
  f32x2 d; asm("v_pk_fma_f32 %0, %1, %2, %3" : "=v"(d) : "v"(a), "v"(b), "v"(c)); return d;
}
__device__ __forceinline__ f32x2 pk_fma_blo(f32x2 a, f32x2 b, f32x2 c) {
  f32x2 d; asm("v_pk_fma_f32 %0, %1, %2, %3 op_sel_hi:[0,1,1]"
               : "=v"(d) : "v"(a), "v"(b), "v"(c)); return d;
}
__device__ __forceinline__ f32x2 pk_fma_bhi(f32x2 a, f32x2 b, f32x2 c) {
  f32x2 d; asm("v_pk_fma_f32 %0, %1, %2, %3 op_sel:[1,0,0]"
               : "=v"(d) : "v"(a), "v"(b), "v"(c)); return d;
}
__device__ __forceinline__ f32x4 ldnt4(const float* p) {
  return __builtin_nontemporal_load(reinterpret_cast<const f32x4*>(p));
}

// ---------------- K1: fused prep (blocks 0-7) + bounds (blocks 8-15).
__global__ void k_pre(const float* __restrict__ Wk, const float* __restrict__ bk,
                      const float* __restrict__ q, const int* __restrict__ batch,
                      float* __restrict__ P, float* __restrict__ c,
                      int* __restrict__ bounds) {
  if (blockIdx.x < 8) {
    int h = blockIdx.x, i = threadIdx.x;
    float s = 0.f;
    #pragma unroll
    for (int d = 0; d < 32; ++d)
      s = fmaf(Wk[i * 256 + h * 32 + d], q[h * 32 + d], s);
    P[h * 256 + i] = s;
    if (i == 0) {
      float cc = 0.f;
      #pragma unroll
      for (int d = 0; d < 32; ++d) cc = fmaf(bk[h * 32 + d], q[h * 32 + d], cc);
      c[h] = cc;
    }
  } else {
    int g = (blockIdx.x - 8) * 256 + threadIdx.x;
    if (g >= NGRAPH) return;
    int lo = 0, hi = N_ATOMS;
    while (lo < hi) {
      int mid = (lo + hi) >> 1;
      if (batch[mid] < g) lo = mid + 1; else hi = mid;
    }
    bounds[2 * g] = lo;
    if (g > 0) bounds[2 * g - 1] = lo;
    if (g == NGRAPH - 1) bounds[2 * g + 1] = N_ATOMS;
  }
}

// transpose-reduce: 8 head-partials/lane over 64 lanes -> full dot of head h at
// every lane (head ownership h(lane) = bit-mix of lane bits 3,4,5). R2-verified.
__device__ __forceinline__ float fold8(float acc[8], int lane) {
  {
    int m = lane & 8;
    float nw[4];
    #pragma unroll
    for (int j = 0; j < 4; ++j) {
      float snd = m ? acc[j] : acc[j + 4];
      float rcv = __shfl_xor(snd, 8, 64);
      nw[j] = (m ? acc[j + 4] : acc[j]) + rcv;
    }
    #pragma unroll
    for (int j = 0; j < 4; ++j) acc[j] = nw[j];
  }
  {
    int m = lane & 16;
    float nw[2];
    #pragma unroll
    for (int j = 0; j < 2; ++j) {
      float snd = m ? acc[j] : acc[j + 2];
      float rcv = __shfl_xor(snd, 16, 64);
      nw[j] = (m ? acc[j + 2] : acc[j]) + rcv;
    }
    acc[0] = nw[0]; acc[1] = nw[1];
  }
  float r;
  {
    int m = lane & 32;
    float snd = m ? acc[0] : acc[1];
    float rcv = __shfl_xor(snd, 32, 64);
    r = (m ? acc[1] : acc[0]) + rcv;
  }
  r += __shfl_xor(r, 1, 64);
  r += __shfl_xor(r, 2, 64);
  r += __shfl_xor(r, 4, 64);
  return r;
}

// ---------------- K2: fused single-pass scores + exp + weighted accumulate.
// Exactly the R8-verified structure (fold8 shfl + elds e-table + chunked
// epilogue + NT loads, no prefetch) with __launch_bounds__(256,4): forces
// VGPR <= 128 so 4 waves/SIMD (16 waves/CU) are guaranteed resident —
// R10 showed +8 VGPRs crossed the 128 cliff and halved occupancy.
__global__ __launch_bounds__(256, 4) void k_fused(const float* __restrict__ x,
                                                  const float* __restrict__ P,
                                                  const float* __restrict__ c,
                                                  const int* __restrict__ bounds,
                                                  float* __restrict__ Ag) {
  int b = blockIdx.x;
  int s = bounds[2 * b], e = bounds[2 * b + 1];
  int t = threadIdx.x, lane = t & 63, wv = t >> 6;
  int h = ((lane >> 1) & 4) | ((lane >> 3) & 2) | ((lane >> 5) & 1);

  f32x2 Pl2[8][2];
  #pragma unroll
  for (int k = 0; k < 8; ++k) {
    f32x4 pv = *reinterpret_cast<const f32x4*>(P + k * 256 + 4 * lane);
    Pl2[k][0] = __builtin_shufflevector(pv, pv, 0, 1);
    Pl2[k][1] = __builtin_shufflevector(pv, pv, 2, 3);
  }
  float cl = c[h];

  f32x2 A2[8][2];
  #pragma unroll
  for (int k = 0; k < 8; ++k) { A2[k][0] = (f32x2)0.f; A2[k][1] = (f32x2)0.f; }
  float dacc = 0.f;

  __shared__ float elds[4][2][8];   // wave-private e-table
  __shared__ float Asc[4][2][256];  // 8 KB chunked epilogue buffer
  __shared__ float dws[4][8];
  __shared__ float dinvs[8];

  for (int n0 = s + 2 * wv; n0 < e; n0 += 8) {
    bool has2 = (n0 + 1) < e;
    int n1 = has2 ? n0 + 1 : n0;
    f32x4 xq0 = ldnt4(x + (size_t)n0 * 256 + 4 * lane);
    f32x4 xq1 = ldnt4(x + (size_t)n1 * 256 + 4 * lane);
    f32x2 x0lo = __builtin_shufflevector(xq0, xq0, 0, 1);
    f32x2 x0hi = __builtin_shufflevector(xq0, xq0, 2, 3);
    f32x2 x1lo = __builtin_shufflevector(xq1, xq1, 0, 1);
    f32x2 x1hi = __builtin_shufflevector(xq1, xq1, 2, 3);

    float acc0[8], acc1[8];
    #pragma unroll
    for (int k = 0; k < 8; ++k) {
      f32x2 p0 = pk_fma(x0hi, Pl2[k][1], pk_mul(x0lo, Pl2[k][0]));
      f32x2 p1 = pk_fma(x1hi, Pl2[k][1], pk_mul(x1lo, Pl2[k][0]));
      acc0[k] = p0[0] + p0[1];
      acc1[k] = p1[0] + p1[1];
    }
    float r0 = fold8(acc0, lane);
    float r1 = fold8(acc1, lane);
    float ev0 = __expf((r0 + cl) * INV_SCALE);
    float ev1 = __expf((r1 + cl) * INV_SCALE);
    ev1 = has2 ? ev1 : 0.f;
    dacc += ev0 + ev1;

    if ((lane & 7) == 0) {
      elds[wv][0][h] = ev0;
      elds[wv][1][h] = ev1;
    }
    f32x4 ea03 = *reinterpret_cast<const f32x4*>(&elds[wv][0][0]);
    f32x4 ea47 = *reinterpret_cast<const f32x4*>(&elds[wv][0][4]);
    f32x4 eb03 = *reinterpret_cast<const f32x4*>(&elds[wv][1][0]);
    f32x4 eb47 = *reinterpret_cast<const f32x4*>(&elds[wv][1][4]);
    f32x2 ea[4] = { __builtin_shufflevector(ea03, ea03, 0, 1),
                    __builtin_shufflevector(ea03, ea03, 2, 3),
                    __builtin_shufflevector(ea47, ea47, 0, 1),
                    __builtin_shufflevector(ea47, ea47, 2, 3) };
    f32x2 eb[4] = { __builtin_shufflevector(eb03, eb03, 0, 1),
                    __builtin_shufflevector(eb03, eb03, 2, 3),
                    __builtin_shufflevector(eb47, eb47, 0, 1),
                    __builtin_shufflevector(eb47, eb47, 2, 3) };
    #pragma unroll
    for (int j = 0; j < 4; ++j) {
      A2[2*j][0]   = pk_fma_blo(ea[j], x0lo, A2[2*j][0]);
      A2[2*j][1]   = pk_fma_blo(ea[j], x0hi, A2[2*j][1]);
      A2[2*j+1][0] = pk_fma_bhi(ea[j], x0lo, A2[2*j+1][0]);
      A2[2*j+1][1] = pk_fma_bhi(ea[j], x0hi, A2[2*j+1][1]);
      A2[2*j][0]   = pk_fma_blo(eb[j], x1lo, A2[2*j][0]);
      A2[2*j][1]   = pk_fma_blo(eb[j], x1hi, A2[2*j][1]);
      A2[2*j+1][0] = pk_fma_bhi(eb[j], x1lo, A2[2*j+1][0]);
      A2[2*j+1][1] = pk_fma_bhi(eb[j], x1hi, A2[2*j+1][1]);
    }
  }

  // ---- epilogue: denom, then 4 head-pair passes of cross-wave reduce.
  if ((lane & 7) == 0) dws[wv][h] = dacc;
  __syncthreads();
  if (t < 8) {
    float ds = dws[0][t] + dws[1][t] + dws[2][t] + dws[3][t];
    dinvs[t] = ds > 0.f ? 1.0f / ds : 0.f;
  }
  #pragma unroll
  for (int p = 0; p < 4; ++p) {
    float4 a0, a1;
    a0.x = A2[2*p][0][0];   a0.y = A2[2*p][0][1];
    a0.z = A2[2*p][1][0];   a0.w = A2[2*p][1][1];
    a1.x = A2[2*p+1][0][0]; a1.y = A2[2*p+1][0][1];
    a1.z = A2[2*p+1][1][0]; a1.w = A2[2*p+1][1][1];
    *reinterpret_cast<float4*>(&Asc[wv][0][4 * lane]) = a0;
    *reinterpret_cast<float4*>(&Asc[wv][1][4 * lane]) = a1;
    __syncthreads();
    float v0 = Asc[0][0][t] + Asc[1][0][t] + Asc[2][0][t] + Asc[3][0][t];
    float v1 = Asc[0][1][t] + Asc[1][1][t] + Asc[2][1][t] + Asc[3][1][t];
    Ag[(size_t)b * 2048 + (2*p) * 256 + t]   = v0 * dinvs[2*p];
    Ag[(size_t)b * 2048 + (2*p+1) * 256 + t] = v1 * dinvs[2*p+1];
    __syncthreads();
  }
}

// ---------------- K5: att = A . Wv + bv (nonempty), out = att . Wo + bo
__global__ __launch_bounds__(256) void k_out(const float* __restrict__ Ag,
                                             const int* __restrict__ bounds,
                                             const float* __restrict__ Wv,
                                             const float* __restrict__ bv,
                                             const float* __restrict__ Wo,
                                             const float* __restrict__ bo,
                                             float* __restrict__ out) {
  __shared__ float Alds[4 * 2048];   // 32 KB
  __shared__ float attlds[4 * 256];  // 4 KB
  __shared__ float eflag[4];
  int b0 = blockIdx.x * 4;
  int t = threadIdx.x;
  #pragma unroll
  for (int r = 0; r < 32; ++r) {
    int idx = r * 256 + t;
    Alds[idx] = Ag[(size_t)b0 * 2048 + idx];
  }
  if (t < 4) {
    int s = bounds[2 * (b0 + t)], e = bounds[2 * (b0 + t) + 1];
    eflag[t] = (e > s) ? 1.0f : 0.0f;
  }
  __syncthreads();
  int h = t >> 5;
  float bvk = bv[t];
  float acc[4];
  #pragma unroll
  for (int g = 0; g < 4; ++g) acc[g] = 0.f;
  for (int i4 = 0; i4 < 64; ++i4) {
    float aa[4][4];
    #pragma unroll
    for (int g = 0; g < 4; ++g) {
      float4 v = *reinterpret_cast<const float4*>(&Alds[g * 2048 + h * 256 + i4 * 4]);
      aa[g][0] = v.x; aa[g][1] = v.y; aa[g][2] = v.z; aa[g][3] = v.w;
    }
    #pragma unroll
    for (int j = 0; j < 4; ++j) {
      float wvv = Wv[(size_t)(i4 * 4 + j) * 256 + t];
      #pragma unroll
      for (int g = 0; g < 4; ++g) acc[g] = fmaf(aa[g][j], wvv, acc[g]);
    }
  }
  #pragma unroll
  for (int g = 0; g < 4; ++g) attlds[g * 256 + t] = acc[g] + bvk * eflag[g];
  __syncthreads();
  float boj = bo[t];
  float o[4];
  #pragma unroll
  for (int g = 0; g < 4; ++g) o[g] = boj;
  for (int k4 = 0; k4 < 64; ++k4) {
    float aa[4][4];
    #pragma unroll
    for (int g = 0; g < 4; ++g) {
      float4 v = *reinterpret_cast<const float4*>(&attlds[g * 256 + k4 * 4]);
      aa[g][0] = v.x; aa[g][1] = v.y; aa[g][2] = v.z; aa[g][3] = v.w;
    }
    #pragma unroll
    for (int j = 0; j < 4; ++j) {
      float wo = Wo[(size_t)(k4 * 4 + j) * 256 + t];
      #pragma unroll
      for (int g = 0; g < 4; ++g) o[g] = fmaf(aa[g][j], wo, o[g]);
    }
  }
  #pragma unroll
  for (int g = 0; g < 4; ++g) out[(size_t)(b0 + g) * 256 + t] = o[g];
}

extern "C" void kernel_launch(void* const* d_in, const int* in_sizes, int n_in,
                              void* d_out, int out_size, void* d_ws, size_t ws_size,
                              hipStream_t stream) {
  const float* x   = (const float*)d_in[0];
  const int*   bat = (const int*)d_in[1];
  const float* q   = (const float*)d_in[2];
  const float* Wk  = (const float*)d_in[3];
  const float* bk  = (const float*)d_in[4];
  const float* Wv  = (const float*)d_in[5];
  const float* bv  = (const float*)d_in[6];
  const float* Wo  = (const float*)d_in[7];
  const float* bo  = (const float*)d_in[8];
  float* out = (float*)d_out;

  float* ws = (float*)d_ws;
  float* P      = ws;                 // 2048 floats
  float* c      = ws + 2048;          // 8 floats
  int*   bounds = (int*)(ws + 4096);  // 4096 ints
  float* Ag     = ws + 8192;          // 2048*2048 floats

  k_pre<<<16, 256, 0, stream>>>(Wk, bk, q, bat, P, c, bounds);
  k_fused<<<NGRAPH, 256, 0, stream>>>(x, P, c, bounds, Ag);
  k_out<<<NGRAPH / 4, 256, 0, stream>>>(Ag, bounds, Wv, bv, Wo, bo, out);
}